// Round 11
// baseline (274.878 us; speedup 1.0000x reference)
//
#include <hip/hip_runtime.h>
#include <hip/hip_bf16.h>

typedef __bf16 bf16_8 __attribute__((ext_vector_type(8)));
typedef __bf16 bf16_4 __attribute__((ext_vector_type(4)));
typedef float f32x4 __attribute__((ext_vector_type(4)));

__device__ __forceinline__ float silu_f(float x) {
    return x / (1.0f + __expf(-x));
}

// Edge map: cell(j*N+i) -> last edge id, or -1. EMPTY=0 (stores k+1; 0xAA ws poison handled by memset-0).
__device__ __forceinline__ unsigned hslot(unsigned cell, unsigned nslots) {
    return (unsigned)(((unsigned long long)(cell * 2654435761u) * nslots) >> 32);
}
__device__ __forceinline__ int map_lookup(unsigned nslots, const int* __restrict__ M,
                                          const unsigned long long* __restrict__ H, unsigned cell) {
    if (nslots == 0) return M[cell] - 1;
    unsigned slot = hslot(cell, nslots);
    for (int pr = 0; pr < 4096; pr++) {
        unsigned long long v = H[slot];
        if (v == 0ull) return -1;
        if ((unsigned)(v >> 32) == cell) return (int)(v & 0xFFFFFFFFu) - 1;
        slot++; if (slot == nslots) slot = 0;
    }
    return -1;
}

__global__ __launch_bounds__(256) void kS(float* __restrict__ out, int n, float val) {
    int i = blockIdx.x * 256 + threadIdx.x;
    if (i < n) out[i] = val;
}

// ---- kA: [0,mapB) map build | +2 Wq=Wb@W0a | +1 bias fold | +coordB coords/segment-sums ----
__global__ __launch_bounds__(256) void kA(
    const float* __restrict__ v, const float* __restrict__ p,
    const int* __restrict__ batch, const int* __restrict__ ei,
    const float* __restrict__ Wc, const float* __restrict__ Wb,
    const float* __restrict__ bb, const float* __restrict__ W0,
    const float* __restrict__ b0,
    int N, int E, int mapB, int coordB,
    unsigned nslots, int* __restrict__ M, unsigned long long* __restrict__ H,
    __bf16* __restrict__ wqT, float* __restrict__ w0L, float* __restrict__ b0p,
    float* __restrict__ cp, float* __restrict__ sums, float* __restrict__ cnts)
{
    __shared__ float sm[16 * 256];
    int b = blockIdx.x, t = threadIdx.x;
    if (b < mapB) {  // last-wins map: max(k+1) per (j,i) cell
        int k = b * 256 + t;
        if (k < E) {
            int jj = ei[k], ii = ei[E + k];
            if ((unsigned)jj >= (unsigned)N) jj = 0;
            if ((unsigned)ii >= (unsigned)N) ii = 0;
            unsigned cell = (unsigned)jj * (unsigned)N + (unsigned)ii;
            if (nslots == 0) {
                atomicMax(&M[cell], k + 1);
            } else {
                unsigned long long mine = ((unsigned long long)cell << 32) | (unsigned)(k + 1);
                unsigned slot = hslot(cell, nslots);
                for (int pr = 0; pr < 4096; pr++) {
                    unsigned long long old = atomicCAS(&H[slot], 0ull, mine);
                    if (old == 0ull) break;
                    if ((unsigned)(old >> 32) == cell) { atomicMax(&H[slot], mine); break; }
                    slot++; if (slot == nslots) slot = 0;
                }
            }
        }
        return;
    }
    b -= mapB;
    if (b < 2) {  // wqT[c*32+q] = (Wb @ W0a)[q][c], bf16 for MFMA B-frags
        int r0 = b * 16;
        for (int idx = t; idx < 4096; idx += 256) sm[idx] = Wb[r0 * 256 + idx];
        __syncthreads();
        float acc[16];
#pragma unroll
        for (int r = 0; r < 16; r++) acc[r] = 0.f;
        for (int m = 0; m < 256; m++) {
            float w = W0[m * 256 + t];
#pragma unroll
            for (int r = 0; r < 16; r++) acc[r] += sm[r * 256 + m] * w;
        }
#pragma unroll
        for (int r = 0; r < 16; r++) wqT[t * 32 + r0 + r] = (__bf16)acc[r];
        return;
    }
    b -= 2;
    if (b < 1) {  // b0' = b0 + bb@W0a ; w0L = W0 row 256
        sm[t] = bb[t];
        __syncthreads();
        float acc = 0.f;
        for (int m = 0; m < 256; m++) acc += sm[m] * W0[m * 256 + t];
        b0p[t] = acc + b0[t];
        w0L[t] = W0[256 * 256 + t];
        return;
    }
    b -= 1;
    {  // coords = v@Wc ; cp = p + coords ; segment sums/counts
        int n = b * 256 + t;
        if (t < 64) sm[t] = Wc[t];
        __syncthreads();
        if (n < N) {
            int mb = batch[n] & 1023;
#pragma unroll
            for (int ax = 0; ax < 3; ax++) {
                float acc = 0.f;
                for (int d2 = 0; d2 < 64; d2++)
                    acc += v[(long long)n * 192 + ax * 64 + d2] * sm[d2];
                float val = p[n * 3 + ax] + acc;
                cp[n * 3 + ax] = val;
                atomicAdd(&sums[mb * 3 + ax], val);
            }
            atomicAdd(&cnts[mb], 1.0f);
        }
    }
}

// ---- kB: [0,gaB) s_h -> {G(bf16), atoms(f32)} | +coordB mean-subtract -> outC(f32) ----
__global__ __launch_bounds__(256) void kB(
    const float* __restrict__ s, const float* __restrict__ Ws,
    const float* __restrict__ bs, const float* __restrict__ W0,
    const float* __restrict__ Wa, const float* __restrict__ ba,
    const int* __restrict__ batch,
    const float* __restrict__ cp, const float* __restrict__ sums, const float* __restrict__ cnts,
    int N, int gaB,
    __bf16* __restrict__ G, float* __restrict__ cp2,
    float* __restrict__ outC, float* __restrict__ outA)
{
    __shared__ float ssrc[16 * 256];
    __shared__ float ssh[16 * 256];
    int b = blockIdx.x, t = threadIdx.x;
    if (b < gaB) {
        int r0 = b * 16;
        for (int idx = t; idx < 4096; idx += 256) {
            int row = r0 + (idx >> 8);
            ssrc[idx] = (row < N) ? s[(long long)row * 256 + (idx & 255)] : 0.f;
        }
        __syncthreads();
        float acc[16];
#pragma unroll
        for (int r = 0; r < 16; r++) acc[r] = 0.f;
        for (int k = 0; k < 256; k++) {
            float w = Ws[k * 256 + t];
#pragma unroll
            for (int r = 0; r < 16; r++) acc[r] += ssrc[r * 256 + k] * w;
        }
        float bsv = bs[t];
#pragma unroll
        for (int r = 0; r < 16; r++) ssh[r * 256 + t] = silu_f(acc[r] + bsv);
        __syncthreads();
        // G = s_h @ W0a (bf16 storage)
#pragma unroll
        for (int r = 0; r < 16; r++) acc[r] = 0.f;
        for (int k = 0; k < 256; k++) {
            float w = W0[k * 256 + t];
#pragma unroll
            for (int r = 0; r < 16; r++) acc[r] += ssh[r * 256 + k] * w;
        }
#pragma unroll
        for (int r = 0; r < 16; r++)
            if (r0 + r < N) G[(long long)(r0 + r) * 256 + t] = (__bf16)acc[r];
        // atoms = s_h @ Wa + ba (f32 out)
        int r = t >> 4, c = t & 15;
        float a2 = 0.f;
        for (int k = 0; k < 256; k++) a2 += ssh[r * 256 + k] * Wa[k * 16 + c];
        if (r0 + r < N) outA[(r0 + r) * 16 + c] = a2 + ba[c];
        return;
    }
    b -= gaB;
    {
        int n = b * 256 + t;
        if (n >= N) return;
        int mb = batch[n] & 1023;
        float cnt = fmaxf(cnts[mb], 1.0f);
#pragma unroll
        for (int ax = 0; ax < 3; ax++) {
            float val = cp[n * 3 + ax] - sums[mb * 3 + ax] / cnt;
            cp2[n * 3 + ax] = val;
            outC[n * 3 + ax] = val;
        }
    }
}

// ---- kC: fused edge pipeline, 64 edges/block, f32 I/O + bf16 MFMA internals ----
__global__ __launch_bounds__(256, 2) void kC(
    const float* __restrict__ e, const int* __restrict__ ei,
    int N, int E, unsigned nslots, const int* __restrict__ M, const unsigned long long* __restrict__ H,
    const __bf16* __restrict__ G, const __bf16* __restrict__ wqTg,
    const float* __restrict__ w0L, const float* __restrict__ b0p,
    const float* __restrict__ cp2, const float* __restrict__ W1, const float* __restrict__ b1,
    float* __restrict__ bonds)
{
    __shared__ __bf16 esym[64 * 40];
    __shared__ __bf16 hbuf[64 * 264];
    __shared__ __bf16 w1T[16 * 264];
    __shared__ float sw0L[256], sb0[256], sb1[16], sd[64];
    __shared__ int si[64], sj[64], sm1[64], sm2[64];

    int t = threadIdx.x;
    int wv = t >> 6, lane = t & 63;
    int l16 = lane & 15, q8 = (lane >> 4) * 8;
    int e0 = blockIdx.x * 64;

    if (t < 64) {
        int k = e0 + t;
        if (k >= E) {
            si[t] = 0; sj[t] = 0; sm1[t] = 0; sm2[t] = -1; sd[t] = 0.f;
        } else {
            int jj = ei[k], ii = ei[E + k];
            if ((unsigned)jj >= (unsigned)N) jj = 0;
            if ((unsigned)ii >= (unsigned)N) ii = 0;
            si[t] = ii; sj[t] = jj;
            int m1 = map_lookup(nslots, M, H, (unsigned)jj * (unsigned)N + (unsigned)ii);
            int m2 = map_lookup(nslots, M, H, (unsigned)ii * (unsigned)N + (unsigned)jj);
            sm1[t] = ((unsigned)m1 < (unsigned)E) ? m1 : 0;
            sm2[t] = ((unsigned)m2 < (unsigned)E) ? m2 : -1;
            float dx = cp2[ii * 3 + 0] - cp2[jj * 3 + 0];
            float dy = cp2[ii * 3 + 1] - cp2[jj * 3 + 1];
            float dz = cp2[ii * 3 + 2] - cp2[jj * 3 + 2];
            sd[t] = dx * dx + dy * dy + dz * dz;
        }
    }
    for (int idx = t; idx < 16 * 256; idx += 256) {  // W1^T staged bf16, padded 5->16 cols
        int c = idx >> 8, k = idx & 255;
        w1T[c * 264 + k] = (c < 5) ? (__bf16)W1[k * 5 + c] : (__bf16)0.f;
    }
    sw0L[t] = w0L[t];
    sb0[t] = b0p[t];
    if (t < 16) sb1[t] = (t < 5) ? b1[t] : 0.f;
    __syncthreads();

    {  // e_sym = 0.5*(e[m1] + e[m2 or 0]), f32 loads -> bf16 LDS
        int er = t >> 2, qg = (t & 3) * 8;
        int m1 = sm1[er], m2 = sm2[er];
        const float* e1p = e + (size_t)m1 * 32 + qg;
        float v1[8], v2[8];
#pragma unroll
        for (int q = 0; q < 8; q++) { v1[q] = e1p[q]; v2[q] = 0.f; }
        if (m2 >= 0) {
            const float* e2p = e + (size_t)m2 * 32 + qg;
#pragma unroll
            for (int q = 0; q < 8; q++) v2[q] = e2p[q];
        }
#pragma unroll
        for (int q = 0; q < 8; q++)
            esym[er * 40 + qg + q] = (__bf16)(0.5f * (v1[q] + v2[q]));
    }
    __syncthreads();

    // GEMM1: esym[64x32] @ Wq[32x256], one 16x16x32 MFMA per tile
    f32x4 acc[4][4];
#pragma unroll
    for (int rt = 0; rt < 4; rt++)
#pragma unroll
        for (int ct = 0; ct < 4; ct++)
            acc[rt][ct] = (f32x4){0.f, 0.f, 0.f, 0.f};
    bf16_8 af[4];
#pragma unroll
    for (int rt = 0; rt < 4; rt++)
        af[rt] = *(const bf16_8*)(esym + (rt * 16 + l16) * 40 + q8);
#pragma unroll
    for (int ct = 0; ct < 4; ct++) {
        int c = (wv * 4 + ct) * 16 + l16;
        bf16_8 bfr = *(const bf16_8*)(wqTg + c * 32 + q8);
#pragma unroll
        for (int rt = 0; rt < 4; rt++)
            acc[rt][ct] = __builtin_amdgcn_mfma_f32_16x16x32_bf16(af[rt], bfr, acc[rt][ct], 0, 0, 0);
    }
    // epilogue: + b0' + d*w0L  (C layout: col=lane&15, row=(lane>>4)*4+reg)
#pragma unroll
    for (int ct = 0; ct < 4; ct++) {
        int col = (wv * 4 + ct) * 16 + l16;
        float w0c = sw0L[col], b0c = sb0[col];
#pragma unroll
        for (int rt = 0; rt < 4; rt++) {
#pragma unroll
            for (int r4 = 0; r4 < 4; r4++) {
                int row = rt * 16 + (lane >> 4) * 4 + r4;
                hbuf[row * 264 + col] = (__bf16)(acc[rt][ct][r4] + b0c + sd[row] * w0c);
            }
        }
    }
    __syncthreads();

    // h = silu(hbuf + G[i] + G[j])
    {
        int c4 = lane * 4;
        for (int it = 0; it < 16; it++) {
            int er = wv * 16 + it;
            int ii = si[er], jj = sj[er];
            bf16_4 gi = *(const bf16_4*)(G + (size_t)ii * 256 + c4);
            bf16_4 gj = *(const bf16_4*)(G + (size_t)jj * 256 + c4);
            bf16_4 hv = *(const bf16_4*)(hbuf + er * 264 + c4);
            bf16_4 o;
#pragma unroll
            for (int q = 0; q < 4; q++) {
                float x = (float)hv[q] + (float)gi[q] + (float)gj[q];
                o[q] = (__bf16)silu_f(x);
            }
            *(bf16_4*)(hbuf + er * 264 + c4) = o;
        }
    }
    __syncthreads();

    // GEMM3: h[64x256] @ W1pad[256x16]; wave w owns row-tile w
    f32x4 acc3 = {0.f, 0.f, 0.f, 0.f};
#pragma unroll
    for (int ks = 0; ks < 8; ks++) {
        bf16_8 a = *(const bf16_8*)(hbuf + (wv * 16 + l16) * 264 + ks * 32 + q8);
        bf16_8 b2 = *(const bf16_8*)(w1T + l16 * 264 + ks * 32 + q8);
        acc3 = __builtin_amdgcn_mfma_f32_16x16x32_bf16(a, b2, acc3, 0, 0, 0);
    }
    if (l16 < 5) {
        float bv = sb1[l16];
#pragma unroll
        for (int r4 = 0; r4 < 4; r4++) {
            int row = wv * 16 + (lane >> 4) * 4 + r4;
            if (e0 + row < E)
                bonds[(size_t)(e0 + row) * 5 + l16] = acc3[r4] + bv;
        }
    }
}

extern "C" void kernel_launch(void* const* d_in, const int* in_sizes, int n_in,
                              void* d_out, int out_size, void* d_ws, size_t ws_size,
                              hipStream_t stream)
{
    // ALL float tensors are raw float32 (round-10 probe: bf16-NaN bits in every one).
    const float* s  = (const float*)d_in[0];
    const float* v  = (const float*)d_in[1];
    const float* p  = (const float*)d_in[2];
    const float* e  = (const float*)d_in[3];
    const int* batch = (const int*)d_in[4];
    const int* ei    = (const int*)d_in[5];
    const float* Ws = (const float*)d_in[6];
    const float* bs = (const float*)d_in[7];
    const float* Wc = (const float*)d_in[8];
    const float* Wa = (const float*)d_in[9];
    const float* ba = (const float*)d_in[10];
    const float* Wb = (const float*)d_in[11];
    const float* bb = (const float*)d_in[12];
    const float* W0 = (const float*)d_in[13];
    const float* b0 = (const float*)d_in[14];
    const float* W1 = (const float*)d_in[15];
    const float* b1 = (const float*)d_in[16];

    float* out = (float*)d_out;
    int sentN = out_size < 8192 ? out_size : 8192;

    int N = in_sizes[0] / 256;
    long long E = in_sizes[5] / 2;
    int code = 0;
    if (in_sizes[6] != 65536) code |= 1;
    if (in_sizes[8] != 64) code |= 2;
    if (in_sizes[11] != 32 * 256) code |= 4;
    if (in_sizes[9] != 16 * 256) code |= 8;
    if (in_sizes[15] != 5 * 256) code |= 16;
    if (in_sizes[13] != 257 * 256) code |= 32;
    if (N < 1 || in_sizes[0] != N * 256) code |= 64;
    if (in_sizes[1] != (long long)N * 192) code |= 128;
    if (in_sizes[2] != N * 3) code |= 256;
    if (in_sizes[3] != E * 32) code |= 512;
    if (in_sizes[4] != N) code |= 1024;
    if ((long long)out_size != 19LL * N + 5LL * E) code |= 2048;
    if (code) {
        kS<<<(sentN + 255) / 256, 256, 0, stream>>>(out, sentN, 3000.0f + 64.0f * (float)code);
        return;
    }
    int Ei = (int)E;

    auto align256 = [](size_t x) { return (x + 255) & ~(size_t)255; };
    size_t G_b  = align256((size_t)N * 512);        // G bf16 [N,256]
    size_t cp_b = align256((size_t)N * 12);         // cp/cp2 f32 [N,3]
    size_t misc = G_b + 16384 + 1024 + 1024 + 2 * cp_b + 12288 + 4096 + 256;
    size_t denseB = (size_t)N * (size_t)N * 4;
    unsigned nslots; size_t mapBytes;
    if (ws_size >= denseB + misc) {
        nslots = 0; mapBytes = denseB;
    } else {
        size_t avail = (ws_size > misc) ? (ws_size - misc) / 8 : 0;
        size_t want = (size_t)Ei * 2;
        size_t ns = avail < want ? avail : want;
        if (ns < (size_t)Ei + (size_t)Ei / 8) {
            unsigned mb = (unsigned)(ws_size >> 20); if (mb > 120) mb = 120;
            kS<<<(sentN + 255) / 256, 256, 0, stream>>>(out, sentN, 1000.0f + 8.0f * (float)mb);
            return;
        }
        nslots = (unsigned)ns; mapBytes = ns * 8;
    }

    char* ws = (char*)d_ws;
    int* M = (int*)ws;
    unsigned long long* H = (unsigned long long*)ws;
    size_t off = align256(mapBytes);
    __bf16* G   = (__bf16*)(ws + off); off += G_b;
    __bf16* wqT = (__bf16*)(ws + off); off += 16384;
    float* w0L  = (float*)(ws + off);  off += 1024;
    float* b0p  = (float*)(ws + off);  off += 1024;
    float* cp   = (float*)(ws + off);  off += cp_b;
    float* cp2  = (float*)(ws + off);  off += cp_b;
    float* sums = (float*)(ws + off);  off += 12288;
    float* cnts = (float*)(ws + off);  off += 4096;

    float* outC = out;                 // coords [N,3] f32
    float* outA = outC + 3 * N;        // atoms  [N,16] f32
    float* outB = outC + 19 * N;       // bonds  [E,5] f32

    (void)hipMemsetAsync(ws, 0x00, mapBytes, stream);       // map empty = 0
    (void)hipMemsetAsync(sums, 0x00, 12288 + 4096, stream); // sums + cnts

    int mapB = (Ei + 255) / 256;
    int coordB = (N + 255) / 256;
    int gaB = (N + 15) / 16;
    kA<<<mapB + 3 + coordB, 256, 0, stream>>>(
        v, p, batch, ei, Wc, Wb, bb, W0, b0,
        N, Ei, mapB, coordB, nslots, M, H, wqT, w0L, b0p, cp, sums, cnts);
    kB<<<gaB + coordB, 256, 0, stream>>>(
        s, Ws, bs, W0, Wa, ba, batch, cp, sums, cnts, N, gaB, G, cp2, outC, outA);
    kC<<<(Ei + 63) / 64, 256, 0, stream>>>(
        e, ei, N, Ei, nslots, M, H, G, wqT, w0L, b0p, cp2, W1, b1, outB);
}